// Round 9
// baseline (103.398 us; speedup 1.0000x reference)
//
#include <hip/hip_runtime.h>

#define NN 1024
#define DG 8
#define FO 64
#define FI 128
#define LALPHA 0.2f
#define BR 16        // output rows per fused block
#define SBS 257      // Sb row stride (u32 words)
#define RDS 68       // reduction row stride (floats)

typedef __attribute__((ext_vector_type(8))) short bf16x8;
typedef __attribute__((ext_vector_type(4))) float f32x4;

static __device__ __forceinline__ unsigned short f2bf(float x) {
  union { float f; unsigned u; } v; v.f = x;
  unsigned r = v.u + 0x7FFFu + ((v.u >> 16) & 1u);  // round-to-nearest-even
  return (unsigned short)(r >> 16);
}
static __device__ __forceinline__ float bf2f(unsigned short h) {
  union { unsigned u; float f; } v; v.u = ((unsigned)h) << 16;
  return v.f;
}

// ---------------------------------------------------------------------------
// K1 (prep): dedupe edges (t<16) + h = atom@W via bf16 hi/lo MFMA, fragments
// straight from global. src/dst via the rank-1 identity (atom@W)@a = atom@(W@a):
// wa = W@a computed once per block in LDS (1 barrier), then accumulated with
// fp32 FMAs alongside the fragment build — no shuffle-reduce chains, no sp/dp
// LDS atomics. hT stores merged to uint2 (4 consecutive nodes per lane).
// ---------------------------------------------------------------------------
__global__ __launch_bounds__(256) void k_prep(const float* __restrict__ atoms,
                                              const float* __restrict__ W,
                                              const float* __restrict__ a,
                                              const int* __restrict__ edges,
                                              int* __restrict__ uniq,
                                              ushort* __restrict__ hT,
                                              ushort* __restrict__ hN,
                                              float* __restrict__ srcv,
                                              float* __restrict__ dstv) {
  __shared__ float wa[2][FI];   // wa[0]=W@a[:64], wa[1]=W@a[64:]
  const int t = threadIdx.x, b = blockIdx.x;
  const int g = b >> 6;
  const int rbase = b * 16;

  // wa precompute: thread t -> row c=t&127 of W, vector half t>>7
  {
    const int c = t & 127, hlf = t >> 7;
    const float4* Wr4 = (const float4*)(W + c * FO);
    const float4* av4 = (const float4*)(a + hlf * FO);
    float s = 0.f;
#pragma unroll
    for (int q = 0; q < FO / 4; q++) {
      float4 wv = Wr4[q], av = av4[q];
      s += wv.x * av.x + wv.y * av.y + wv.z * av.z + wv.w * av.w;
    }
    wa[hlf][c] = s;
  }

  if (t < 16) {
    const int rr = rbase + t;
    int e[DG];
#pragma unroll
    for (int s = 0; s < DG; s++) e[s] = edges[rr * DG + s];
#pragma unroll
    for (int s = 0; s < DG; s++) {
      int v = e[s];
      bool dup = false;
#pragma unroll
      for (int q = 0; q < DG; q++)
        if (q < s && e[q] == v) dup = true;
      uniq[rr * DG + s] = dup ? -1 : v;
    }
  }
  __syncthreads();

  const int w = t >> 6, lane = t & 63, quad = lane >> 4, l16 = lane & 15;
  const float* __restrict__ Ar = atoms + (size_t)(rbase + l16) * FI;
  const float* __restrict__ Wc = W + w * 16 + l16;
  f32x4 acc = {0.f, 0.f, 0.f, 0.f};
  float sp = 0.f, dp = 0.f;   // per-row (l16) src/dst partials over this thread's k
#pragma unroll
  for (int kc = 0; kc < 4; kc++) {
    const int k0 = kc * 32 + quad * 8;
    float4 a0 = *(const float4*)(Ar + k0);
    float4 a1 = *(const float4*)(Ar + k0 + 4);
    float av[8] = {a0.x, a0.y, a0.z, a0.w, a1.x, a1.y, a1.z, a1.w};
    float wv[8];
#pragma unroll
    for (int e = 0; e < 8; e++) wv[e] = Wc[(k0 + e) * FO];
    bf16x8 ahi, alo, bhi, blo;
#pragma unroll
    for (int e = 0; e < 8; e++) {
      sp += av[e] * wa[0][k0 + e];
      dp += av[e] * wa[1][k0 + e];
      ushort h = f2bf(av[e]);
      ahi[e] = (short)h;
      alo[e] = (short)f2bf(av[e] - bf2f(h));
      ushort g2 = f2bf(wv[e]);
      bhi[e] = (short)g2;
      blo[e] = (short)f2bf(wv[e] - bf2f(g2));
    }
    acc = __builtin_amdgcn_mfma_f32_16x16x32_bf16(ahi, bhi, acc, 0, 0, 0);
    acc = __builtin_amdgcn_mfma_f32_16x16x32_bf16(ahi, blo, acc, 0, 0, 0);
    acc = __builtin_amdgcn_mfma_f32_16x16x32_bf16(alo, bhi, acc, 0, 0, 0);
  }

  // src/dst: reduce over the 4 quads holding row l16's k-slices (wave 0 only writes)
  sp += __shfl_xor(sp, 16); sp += __shfl_xor(sp, 32);
  dp += __shfl_xor(dp, 16); dp += __shfl_xor(dp, 32);
  if (w == 0 && quad == 0) {
    srcv[rbase + l16] = sp;
    dstv[rbase + l16] = dp;
  }

  // h epilogue: lane holds rows quad*4+r (consecutive), col f = w*16+l16
  const int f = w * 16 + l16;
  union { uint2 v; ushort us[4]; } hpk;
#pragma unroll
  for (int r = 0; r < 4; r++) {
    float v = acc[r];
    ushort hv = f2bf(v);
    hpk.us[r] = hv;
    int rb = rbase + quad * 4 + r;
    hN[(size_t)rb * FO + f] = hv;
  }
  const int n0 = rbase + quad * 4;
  *(uint2*)(hT + ((size_t)g * FO + f) * NN + (n0 & (NN - 1))) = hpk.v;
}

// ---------------------------------------------------------------------------
// K2 (fused): identical structure to round 8 (scatter -> u8 byte counters;
// k-split GEMM with exp-LUT A-fragments; cross-wave LDS reduce; fp32 epilogue).
// Only change: Sb zeroing via uint4.
// ---------------------------------------------------------------------------
__global__ __launch_bounds__(256, 4) void k_fused(const int* __restrict__ uniq,
                                                  const float* __restrict__ srcv,
                                                  const float* __restrict__ dstv,
                                                  const ushort* __restrict__ hT,
                                                  const ushort* __restrict__ hN,
                                                  float* __restrict__ out) {
  __shared__ __align__(16) unsigned Sb[BR * SBS];   // 16448 B byte counters
  __shared__ __align__(16) float red[4][BR][RDS];   // 17408 B k-split partials
  __shared__ float zred[4][16];
  __shared__ int n1[BR][DG];
  __shared__ float attw[BR][DG];
  __shared__ float lutF[80];                        // exp(n) fp32, n=0..79
  __shared__ ushort lutB[80];                       // bf16(exp(n))

  const int t = threadIdx.x, b = blockIdx.x;
  const int g = b >> 6, rbase = (b & 63) * BR;
  const int* __restrict__ Ug = uniq + (size_t)g * NN * DG;

  {
    uint4* Sb4 = (uint4*)Sb;
    for (int i = t; i < (BR * SBS) / 4; i += 256) Sb4[i] = make_uint4(0, 0, 0, 0);
    if (t < BR * SBS - ((BR * SBS) / 4) * 4)
      Sb[((BR * SBS) / 4) * 4 + t] = 0u;
  }
  if (t < BR * DG) n1[t >> 3][t & 7] = Ug[(rbase + (t >> 3)) * DG + (t & 7)];
  if (t >= 128 && t < 208) {
    int c = t - 128;
    float e = __expf((float)c);
    lutF[c] = e;
    lutB[c] = f2bf(e);
  }
  __syncthreads();

  // --- scatter: 1024 items (r, s=e>>3, slot=e&7), levels 1..3 fused ---
#pragma unroll
  for (int q = 0; q < 4; q++) {
    int idx = t + 256 * q;
    int r = idx >> 6, e = idx & 63;
    int j = n1[r][e >> 3];
    if (j >= 0) {
      if ((e & 7) == 0)  // level-1, once per (r,s)
        atomicAdd(&Sb[r * SBS + (j >> 2)], 1u << ((j & 3) * 8));
      int k = Ug[j * DG + (e & 7)];
      if (k >= 0) {
        atomicAdd(&Sb[r * SBS + (k >> 2)], 1u << ((k & 3) * 8));  // level-2
        int4 m0 = *(const int4*)(Ug + k * DG);
        int4 m1 = *(const int4*)(Ug + k * DG + 4);
        int ll[8] = {m0.x, m0.y, m0.z, m0.w, m1.x, m1.y, m1.z, m1.w};
#pragma unroll
        for (int e2 = 0; e2 < 8; e2++)  // level-3
          if (ll[e2] >= 0) atomicAdd(&Sb[r * SBS + (ll[e2] >> 2)], 1u << ((ll[e2] & 3) * 8));
      }
    }
  }
  // att softmax (t<16, one row each)
  if (t < BR) {
    int r = t;
    float si = srcv[g * NN + rbase + r];
    float ev[DG];
    float m = -1e30f;
#pragma unroll
    for (int s = 0; s < DG; s++) {
      int j = n1[r][s];
      if (j >= 0) {
        float x = si + dstv[g * NN + j];
        x = x > 0.f ? x : LALPHA * x;
        ev[s] = x;
        m = fmaxf(m, x);
      } else ev[s] = -1e30f;
    }
    float sm = 0.f;
#pragma unroll
    for (int s = 0; s < DG; s++) {
      float e = (n1[r][s] >= 0) ? __expf(ev[s] - m) : 0.f;
      ev[s] = e;
      sm += e;
    }
    float inv = 1.f / sm;
#pragma unroll
    for (int s = 0; s < DG; s++) attw[r][s] = ev[s] * inv;
  }
  __syncthreads();

  // --- attH in registers: thread t -> (row rr_, cols f0_..f0_+4) ---
  const int rr_ = t >> 4, f0_ = (t & 15) * 4;
  float ah0 = 0.f, ah1 = 0.f, ah2 = 0.f, ah3 = 0.f;
#pragma unroll
  for (int s = 0; s < DG; s++) {
    int j = n1[rr_][s];
    if (j >= 0) {
      float wgt = attw[rr_][s];
      uint2 hv = *(const uint2*)(hN + ((size_t)(g * NN + j)) * FO + f0_);
      ah0 += wgt * bf2f((ushort)(hv.x & 0xffffu));
      ah1 += wgt * bf2f((ushort)(hv.x >> 16));
      ah2 += wgt * bf2f((ushort)(hv.y & 0xffffu));
      ah3 += wgt * bf2f((ushort)(hv.y >> 16));
    }
  }

  // --- k-split GEMM: wave v covers nodes [v*256, v*256+256) ---
  const int v = t >> 6, lane = t & 63, quad = lane >> 4, l16 = lane & 15;
  const int k0 = v * 256;
  const ushort* __restrict__ hb = hT + ((size_t)g * FO) * NN;
  f32x4 acc[4] = {{0.f, 0.f, 0.f, 0.f}, {0.f, 0.f, 0.f, 0.f},
                  {0.f, 0.f, 0.f, 0.f}, {0.f, 0.f, 0.f, 0.f}};
  float zacc = 0.f;
#pragma unroll
  for (int ks = 0; ks < 256; ks += 32) {
    const int wd = l16 * SBS + ((k0 + ks) >> 2) + quad * 2;
    unsigned s0 = Sb[wd], s1 = Sb[wd + 1];
    const int c0 = s0 & 255u, c1 = (s0 >> 8) & 255u, c2 = (s0 >> 16) & 255u, c3 = s0 >> 24;
    const int c4 = s1 & 255u, c5 = (s1 >> 8) & 255u, c6 = (s1 >> 16) & 255u, c7 = s1 >> 24;
    bf16x8 af;
    af[0] = (short)lutB[c0]; af[1] = (short)lutB[c1];
    af[2] = (short)lutB[c2]; af[3] = (short)lutB[c3];
    af[4] = (short)lutB[c4]; af[5] = (short)lutB[c5];
    af[6] = (short)lutB[c6]; af[7] = (short)lutB[c7];
    zacc += (lutF[c0] + lutF[c1]) + (lutF[c2] + lutF[c3]) +
            (lutF[c4] + lutF[c5]) + (lutF[c6] + lutF[c7]);
    const ushort* hp = hb + (size_t)l16 * NN + k0 + ks + quad * 8;
#pragma unroll
    for (int ct = 0; ct < 4; ct++) {
      bf16x8 bf = *(const bf16x8*)(hp + (size_t)(ct * 16) * NN);
      acc[ct] = __builtin_amdgcn_mfma_f32_16x16x32_bf16(af, bf, acc[ct], 0, 0, 0);
    }
  }
  zacc += __shfl_xor(zacc, 16);
  zacc += __shfl_xor(zacc, 32);
  if (lane < 16) zred[v][lane] = zacc;
#pragma unroll
  for (int ct = 0; ct < 4; ct++)
#pragma unroll
    for (int r = 0; r < 4; r++)
      red[v][quad * 4 + r][ct * 16 + l16] = acc[ct][r];
  __syncthreads();

  // --- epilogue: thread t -> (row rr_, cols f0_..f0_+4), coalesced float4 ---
  const float Z = zred[0][rr_] + zred[1][rr_] + zred[2][rr_] + zred[3][rr_];
  const float hz = 0.5f / Z;
  f32x4 s = *(const f32x4*)&red[0][rr_][f0_];
  f32x4 s1v = *(const f32x4*)&red[1][rr_][f0_];
  f32x4 s2v = *(const f32x4*)&red[2][rr_][f0_];
  f32x4 s3v = *(const f32x4*)&red[3][rr_][f0_];
  float o0 = 0.5f * ah0 + (s[0] + s1v[0] + s2v[0] + s3v[0]) * hz;
  float o1 = 0.5f * ah1 + (s[1] + s1v[1] + s2v[1] + s3v[1]) * hz;
  float o2 = 0.5f * ah2 + (s[2] + s1v[2] + s2v[2] + s3v[2]) * hz;
  float o3 = 0.5f * ah3 + (s[3] + s1v[3] + s2v[3] + s3v[3]) * hz;
  o0 = o0 > 0.f ? o0 : __expf(o0) - 1.f;
  o1 = o1 > 0.f ? o1 : __expf(o1) - 1.f;
  o2 = o2 > 0.f ? o2 : __expf(o2) - 1.f;
  o3 = o3 > 0.f ? o3 : __expf(o3) - 1.f;
  *(float4*)(out + ((size_t)(g * NN + rbase + rr_)) * FO + f0_) =
      make_float4(o0, o1, o2, o3);
}

// ---------------------------------------------------------------------------
extern "C" void kernel_launch(void* const* d_in, const int* in_sizes, int n_in,
                              void* d_out, int out_size, void* d_ws, size_t ws_size,
                              hipStream_t stream) {
  const float* atoms = (const float*)d_in[0];
  const int* edges = (const int*)d_in[1];
  const float* W = (const float*)d_in[2];
  const float* a = (const float*)d_in[3];
  float* out = (float*)d_out;

  const int nrows = in_sizes[0] / FI;   // B*N = 16384
  const int ngraph = nrows / NN;        // 16

  ushort* hT = (ushort*)d_ws;                                   // ngraph*FO*NN
  ushort* hN = hT + (size_t)ngraph * FO * NN;                   // nrows*FO
  float* srcv = (float*)(hN + (size_t)nrows * FO);              // nrows
  float* dstv = srcv + nrows;                                   // nrows
  int* uniq = (int*)(dstv + nrows);                             // nrows*DG

  k_prep<<<nrows / 16, 256, 0, stream>>>(atoms, W, a, edges, uniq, hT, hN, srcv, dstv);
  k_fused<<<ngraph * (NN / BR), 256, 0, stream>>>(uniq, srcv, dstv, hT, hN, out);
}